// Round 8
// baseline (624.904 us; speedup 1.0000x reference)
//
#include <hip/hip_runtime.h>

#define B_   64
#define C_   12
#define NC_  16
#define N0_  2048
#define N1_  1000
#define N2_  500
#define N3_  100
#define AGENT __HIP_MEMORY_SCOPE_AGENT

#define A_TASKS 6000   // 12 classes x 500 row-pairs
#define B_TASKS 3000   // 12 classes x 250 row-pairs
#define NWAVES  4096   // 256 blocks x 16 waves

__device__ __forceinline__ float wred(float v) {
#pragma unroll
    for (int off = 32; off > 0; off >>= 1) v += __shfl_xor(v, off, 64);
    return v;
}

// ===== K0: zero the 13824-B control region =====
__global__ void k_zero(int* __restrict__ z) {
    for (int i = threadIdx.x; i < 3456; i += 256) z[i] = 0;
}

// ===== K1: everything, one kernel. 256 blocks x 1024 threads, all co-resident. =====
// zctrl layout (ints, 16-int padded counters):
//   cntA[c*16]  @0      (192)   per-class l1b task count (500 = done)
//   cntB[c*16]  @192    (192)   per-class l2b task count (250 = done)
//   cntb[b*16]  @384    (1024)  per-b y1-quarter count (4 = done)
//   cnt2[b*16]  @1408   (1024)  per-b y2-quarter count
//   flag[b*16]  @2432   (1024)  1 + expert id, 0 = not ready
__global__ __launch_bounds__(1024)
void k_all(const float* __restrict__ x, const int* __restrict__ cls,
           const float* __restrict__ W1b, const float* __restrict__ b1b,
           const float* __restrict__ W2b, const float* __restrict__ b2b,
           const float* __restrict__ W3b, const float* __restrict__ b3b,
           const float* __restrict__ W1r, const float* __restrict__ b1r,
           const float* __restrict__ W2r, const float* __restrict__ b2r,
           float* __restrict__ h1, float* __restrict__ h2,
           float* __restrict__ y1part, float* __restrict__ y2part,
           int* __restrict__ zctrl,
           float* __restrict__ out_y1, float* __restrict__ out_y2) {
    const int tid  = threadIdx.x;
    const int lane = tid & 63;
    const int wave = tid >> 6;                       // 0..15
    const int wg   = blockIdx.x * 16 + wave;         // 0..4095
    const int b    = blockIdx.x >> 2;                // C/D: 4 blocks per b
    const int q    = blockIdx.x & 3;
    const int cls_lane = cls[lane];

    int* cntA = zctrl;
    int* cntB = zctrl + 192;
    int* cntb = zctrl + 384;
    int* cnt2 = zctrl + 1408;
    int* flag = zctrl + 2432;

    __shared__ __align__(16) float s_x[N0_];         // 8 KB (for phase D)
    __shared__ float s_h2[N2_];                      // 2 KB
    __shared__ float s_y1p[NC_];
    __shared__ float s_y2p[16][4];
    __shared__ int   s_e;

    {   // stage x[b] once; consumed in phase D (first __syncthreads is in C)
        const float4* xs = (const float4*)(x + (size_t)b * N0_);
        if (tid < 512) ((float4*)s_x)[tid] = xs[tid];
    }

    // ================= Phase A: h1 = relu(x·W1b^T + b1b) =================
    for (int t = wg; t < A_TASKS; t += NWAVES) {
        const int c  = t / 500;
        const int j0 = (t % 500) * 2;
        const unsigned long long m = __ballot(cls_lane == c);
        if (m != 0ull) {
            const float4* wr0 = (const float4*)(W1b + ((size_t)c * N1_ + j0) * N0_);
            const float4* wr1 = wr0 + (N0_ / 4);
            float4 w0[8], w1[8];
#pragma unroll
            for (int f = 0; f < 8; ++f) { w0[f] = wr0[f * 64 + lane]; w1[f] = wr1[f * 64 + lane]; }
            const float bias0 = b1b[c * N1_ + j0];
            const float bias1 = b1b[c * N1_ + j0 + 1];
            for (unsigned long long mm = m; mm; mm &= (mm - 1ull)) {
                const int bb = (int)__builtin_ctzll(mm);
                const float4* xr = (const float4*)(x + (size_t)bb * N0_);
                float a0 = 0.f, a1 = 0.f;
#pragma unroll
                for (int f = 0; f < 8; ++f) {
                    const float4 xv = xr[f * 64 + lane];
                    a0 += w0[f].x * xv.x + w0[f].y * xv.y + w0[f].z * xv.z + w0[f].w * xv.w;
                    a1 += w1[f].x * xv.x + w1[f].y * xv.y + w1[f].z * xv.z + w1[f].w * xv.w;
                }
                const float s0 = wred(a0), s1 = wred(a1);
                if (lane == 0) {
                    h1[(size_t)bb * N1_ + j0]     = fmaxf(s0 + bias0, 0.f);
                    h1[(size_t)bb * N1_ + j0 + 1] = fmaxf(s1 + bias1, 0.f);
                }
            }
        }
        if (lane == 0) {
            __threadfence();
            __hip_atomic_fetch_add(&cntA[c * 16], 1, __ATOMIC_ACQ_REL, AGENT);
        }
    }

    // ================= Phase B: h2 = relu(h1·W2b^T + b2b), class-batched =================
    if (wg < B_TASKS) {
        const int t  = B_TASKS - 1 - wg;             // reversed: early waves -> late classes
        const int c  = t / 250;
        const int j0 = (t % 250) * 2;
        if (lane == 0) {
            while (__hip_atomic_load(&cntA[c * 16], __ATOMIC_ACQUIRE, AGENT) < 500)
                __builtin_amdgcn_s_sleep(8);
        }
        const unsigned long long m = __ballot(cls_lane == c);
        const float4 z4 = make_float4(0.f, 0.f, 0.f, 0.f);
        const float4* wr0 = (const float4*)(W2b + ((size_t)c * N2_ + j0) * N1_);
        const float4* wr1 = wr0 + (N1_ / 4);
        float4 w0[4], w1[4];
#pragma unroll
        for (int f = 0; f < 4; ++f) {
            const int id4 = f * 64 + lane;
            const bool v = (id4 < N1_ / 4);
            w0[f] = v ? wr0[id4] : z4;
            w1[f] = v ? wr1[id4] : z4;
        }
        const float bias0 = b2b[c * N2_ + j0];
        const float bias1 = b2b[c * N2_ + j0 + 1];
        for (unsigned long long mm = m; mm; mm &= (mm - 1ull)) {
            const int bb = (int)__builtin_ctzll(mm);
            const float4* xr = (const float4*)(h1 + (size_t)bb * N1_);
            float a0 = 0.f, a1 = 0.f;
#pragma unroll
            for (int f = 0; f < 4; ++f) {
                const int id4 = f * 64 + lane;
                const float4 xv = (id4 < N1_ / 4) ? xr[id4] : z4;
                a0 += w0[f].x * xv.x + w0[f].y * xv.y + w0[f].z * xv.z + w0[f].w * xv.w;
                a1 += w1[f].x * xv.x + w1[f].y * xv.y + w1[f].z * xv.z + w1[f].w * xv.w;
            }
            const float s0 = wred(a0), s1 = wred(a1);
            if (lane == 0) {
                h2[(size_t)bb * N2_ + j0]     = fmaxf(s0 + bias0, 0.f);
                h2[(size_t)bb * N2_ + j0 + 1] = fmaxf(s1 + bias1, 0.f);
            }
        }
        if (lane == 0) {
            __threadfence();
            __hip_atomic_fetch_add(&cntB[c * 16], 1, __ATOMIC_ACQ_REL, AGENT);
        }
    }

    // ================= Phase C: y1 quarter + argmax + flag =================
    const int cb = cls[b];
    if (wave == 0 && lane == 0) {
        while (__hip_atomic_load(&cntB[cb * 16], __ATOMIC_ACQUIRE, AGENT) < 250)
            __builtin_amdgcn_s_sleep(8);
    }
    __syncthreads();
    if (tid < N2_) s_h2[tid] = h2[(size_t)b * N2_ + tid];
    __syncthreads();

    {   // wave m computes y1 quarter-partial for output m over k = 4*idx+q
        const float* w3r = W3b + ((size_t)cb * NC_ + wave) * N2_;
        float a = s_h2[4 * lane + q] * w3r[4 * lane + q];            // idx = lane (<125)
        if (lane < 61) {                                             // idx = lane+64 (<125)
            const int k2 = 4 * (lane + 64) + q;
            a += s_h2[k2] * w3r[k2];
        }
        a = wred(a);
        if (lane == 0) s_y1p[wave] = a;
    }
    __syncthreads();

    if (wave == 0) {
        if (lane < NC_) y1part[(size_t)(b * 4 + q) * NC_ + lane] = s_y1p[lane];
        __threadfence();
        int old = 0;
        if (lane == 0) old = __hip_atomic_fetch_add(&cntb[b * 16], 1, __ATOMIC_ACQ_REL, AGENT);
        old = __shfl(old, 0, 64);
        if (old == 3) {                              // last quarter: finalize y1
            float v = -1e30f;
            if (lane < NC_) {
                v = b3b[cb * NC_ + lane];
#pragma unroll
                for (int qq = 0; qq < 4; ++qq) v += y1part[(size_t)(b * 4 + qq) * NC_ + lane];
                out_y1[b * NC_ + lane] = v;
            }
            int mi = lane;                           // first-occurrence argmax over 16
#pragma unroll
            for (int off = 8; off > 0; off >>= 1) {
                const float ov = __shfl_xor(v,  off, 16);
                const int   om = __shfl_xor(mi, off, 16);
                if (ov > v || (ov == v && om < mi)) { v = ov; mi = om; }
            }
            if (lane == 0)
                __hip_atomic_store(&flag[b * 16], 1 + cb * NC_ + mi, __ATOMIC_RELEASE, AGENT);
        }
        int fv = 0;
        if (lane == 0) {
            while ((fv = __hip_atomic_load(&flag[b * 16], __ATOMIC_ACQUIRE, AGENT)) == 0)
                __builtin_amdgcn_s_sleep(1);
            s_e = fv - 1;
        }
    }
    __syncthreads();
    const int e = s_e;

    // ================= Phase D: r quarter + y2 =================
    float y2p = 0.f;
    for (int idx = wave; idx < 25; idx += 16) {
        const int j = 4 * idx + q;
        const float4* wr = (const float4*)(W1r + ((size_t)e * N3_ + j) * N0_);
        const float4* xr = (const float4*)s_x;
        float a = 0.f;
#pragma unroll
        for (int f = 0; f < 8; ++f) {
            const int id4 = f * 64 + lane;
            const float4 wv = wr[id4], xv = xr[id4];
            a += wv.x * xv.x + wv.y * xv.y + wv.z * xv.z + wv.w * xv.w;
        }
        const float rv = fmaxf(wred(a) + b1r[e * N3_ + j], 0.f);     // all lanes
        if (lane < 3) y2p += rv * W2r[((size_t)e * 3 + lane) * N3_ + j];
    }
    if (lane < 4) s_y2p[wave][lane] = (lane < 3) ? y2p : 0.f;
    __syncthreads();

    if (wave == 0) {
        if (lane < 3) {
            float t = 0.f;
#pragma unroll
            for (int w = 0; w < 16; ++w) t += s_y2p[w][lane];
            y2part[(size_t)(b * 4 + q) * 4 + lane] = t;
        }
        __threadfence();
        int old = 0;
        if (lane == 0) old = __hip_atomic_fetch_add(&cnt2[b * 16], 1, __ATOMIC_ACQ_REL, AGENT);
        old = __shfl(old, 0, 64);
        if (old == 3 && lane < 3) {                  // last quarter: finalize y2
            float t = b2r[e * 3 + lane];
#pragma unroll
            for (int qq = 0; qq < 4; ++qq) t += y2part[(size_t)(b * 4 + qq) * 4 + lane];
            out_y2[b * 3 + lane] = t;
        }
    }
}

extern "C" void kernel_launch(void* const* d_in, const int* in_sizes, int n_in,
                              void* d_out, int out_size, void* d_ws, size_t ws_size,
                              hipStream_t stream) {
    const float* x   = (const float*)d_in[0];
    const int*   cls = (const int*)  d_in[1];
    const float* W1b = (const float*)d_in[2];
    const float* b1b = (const float*)d_in[3];
    const float* W2b = (const float*)d_in[4];
    const float* b2b = (const float*)d_in[5];
    const float* W3b = (const float*)d_in[6];
    const float* b3b = (const float*)d_in[7];
    const float* W1r = (const float*)d_in[8];
    const float* b1r = (const float*)d_in[9];
    const float* W2r = (const float*)d_in[10];
    const float* b2r = (const float*)d_in[11];

    float* out_y1 = (float*)d_out;                 // [0, 1024)
    float* out_y2 = (float*)d_out + B_ * NC_;      // [1024, 1216)

    char*  ws     = (char*)d_ws;
    float* h1     = (float*)(ws);                  // 256000 B
    float* h2     = (float*)(ws + 256000);         // 128000 B
    float* y1part = (float*)(ws + 384000);         // 16384 B
    float* y2part = (float*)(ws + 400384);         //  4096 B
    int*   zctrl  = (int*)  (ws + 404480);         // 13824 B

    hipLaunchKernelGGL(k_zero, dim3(1), dim3(256), 0, stream, zctrl);
    hipLaunchKernelGGL(k_all, dim3(256), dim3(1024), 0, stream,
                       x, cls, W1b, b1b, W2b, b2b, W3b, b3b, W1r, b1r, W2r, b2r,
                       h1, h2, y1part, y2part, zctrl, out_y1, out_y2);
}

// Round 14
// 68.877 us; speedup vs baseline: 9.0728x; 9.0728x over previous
//
#include <hip/hip_runtime.h>

#define B_   64
#define C_   12
#define NC_  16
#define N0_  2048
#define N1_  1000
#define N2_  500
#define N3_  100

__device__ __forceinline__ float wred(float v) {
#pragma unroll
    for (int off = 32; off > 0; off >>= 1) v += __shfl_xor(v, off, 64);
    return v;
}

// ===== K1: h1 = relu(x·W1b^T + b1b). grid 1500×256, class-interleaved wave-tasks. =====
// Wave-task t = blockIdx.x*4 + wave in [0,6000): c = t%12, j0 = (t/12)*2.
// No LDS, no syncthreads, no atomics.
__global__ __launch_bounds__(256)
void k_l1b(const float* __restrict__ x, const int* __restrict__ cls,
           const float* __restrict__ W1b, const float* __restrict__ b1b,
           float* __restrict__ h1) {
    const int lane = threadIdx.x & 63;
    const int wave = threadIdx.x >> 6;
    const int t    = blockIdx.x * 4 + wave;        // 0..5999
    const int c    = t % C_;                       // interleaved classes
    const int j0   = (t / C_) * 2;                 // 0..998

    const unsigned long long m = __ballot(cls[lane] == c);
    if (m == 0ull) return;

    const float4* wr0 = (const float4*)(W1b + ((size_t)c * N1_ + j0) * N0_);
    const float4* wr1 = wr0 + (N0_ / 4);
    float4 w0[8], w1[8];
#pragma unroll
    for (int f = 0; f < 8; ++f) { w0[f] = wr0[f * 64 + lane]; w1[f] = wr1[f * 64 + lane]; }
    const float bias0 = b1b[c * N1_ + j0];
    const float bias1 = b1b[c * N1_ + j0 + 1];

    for (unsigned long long mm = m; mm; mm &= (mm - 1ull)) {
        const int b = (int)__builtin_ctzll(mm);
        const float4* xr = (const float4*)(x + (size_t)b * N0_);
        float a0 = 0.f, a1 = 0.f;
#pragma unroll
        for (int f = 0; f < 8; ++f) {
            const float4 xv = xr[f * 64 + lane];
            a0 += w0[f].x * xv.x + w0[f].y * xv.y + w0[f].z * xv.z + w0[f].w * xv.w;
            a1 += w1[f].x * xv.x + w1[f].y * xv.y + w1[f].z * xv.z + w1[f].w * xv.w;
        }
        const float s0 = wred(a0), s1 = wred(a1);
        if (lane == 0) {
            h1[(size_t)b * N1_ + j0]     = fmaxf(s0 + bias0, 0.f);
            h1[(size_t)b * N1_ + j0 + 1] = fmaxf(s1 + bias1, 0.f);
        }
    }
}

// ===== K2: one block per b — h2 -> y1 -> argmax -> r -> y2, all in-block. =====
// grid 64 × 1024 (16 waves). No atomics, no global intermediates. (Round-5 proven.)
__global__ __launch_bounds__(1024)
void k_perb(const float* __restrict__ x, const int* __restrict__ cls,
            const float* __restrict__ h1,
            const float* __restrict__ W2b, const float* __restrict__ b2b,
            const float* __restrict__ W3b, const float* __restrict__ b3b,
            const float* __restrict__ W1r, const float* __restrict__ b1r,
            const float* __restrict__ W2r, const float* __restrict__ b2r,
            float* __restrict__ out_y1, float* __restrict__ out_y2) {
    const int b    = blockIdx.x;
    const int tid  = threadIdx.x;
    const int lane = tid & 63;
    const int wave = tid >> 6;                     // 0..15
    const int c    = cls[b];

    __shared__ __align__(16) float s_x[N0_];       // 8 KB
    __shared__ __align__(16) float s_h1[N1_];      // 4 KB
    __shared__ float s_h2[N2_];                    // 2 KB
    __shared__ float s_y1[NC_];
    __shared__ float s_r[N3_];
    __shared__ int   s_e;

    for (int i = tid; i < N0_; i += 1024) s_x[i]  = x[(size_t)b * N0_ + i];
    for (int i = tid; i < N1_; i += 1024) s_h1[i] = h1[(size_t)b * N1_ + i];
    __syncthreads();

    // ---- h2[b][j] = relu(h1·W2b[c][j] + b2b), 500 rows, 2/wave/iter ----
    {
        const float4* xr = (const float4*)s_h1;    // 250 float4
        for (int j0 = wave * 2; j0 < N2_; j0 += 32) {
            const float4* wr0 = (const float4*)(W2b + ((size_t)c * N2_ + j0) * N1_);
            const float4* wr1 = wr0 + (N1_ / 4);
            float a0 = 0.f, a1 = 0.f;
#pragma unroll
            for (int f = 0; f < 4; ++f) {
                const int idx = f * 64 + lane;
                if (idx < N1_ / 4) {
                    const float4 xv = xr[idx];
                    const float4 w0 = wr0[idx], w1 = wr1[idx];
                    a0 += w0.x * xv.x + w0.y * xv.y + w0.z * xv.z + w0.w * xv.w;
                    a1 += w1.x * xv.x + w1.y * xv.y + w1.z * xv.z + w1.w * xv.w;
                }
            }
            const float s0 = wred(a0), s1 = wred(a1);
            if (lane == 0) {
                s_h2[j0]     = fmaxf(s0 + b2b[c * N2_ + j0],     0.f);
                s_h2[j0 + 1] = fmaxf(s1 + b2b[c * N2_ + j0 + 1], 0.f);
            }
        }
    }
    __syncthreads();

    // ---- y1[b][m] = h2·W3b[c][m] + b3b, wave m handles m ----
    if (wave < NC_) {
        const float* wrow = W3b + ((size_t)c * NC_ + wave) * N2_;
        float a = 0.f;
        for (int k = lane; k < N2_; k += 64) a += s_h2[k] * wrow[k];
        const float s = wred(a) + b3b[c * NC_ + wave];
        if (lane == 0) { s_y1[wave] = s; out_y1[b * NC_ + wave] = s; }
    }
    __syncthreads();

    // ---- argmax (first occurrence) by wave 0, lanes 0..15 ----
    if (wave == 0) {
        float v  = (lane < NC_) ? s_y1[lane] : -1e30f;
        int   mi = lane;
#pragma unroll
        for (int off = 8; off > 0; off >>= 1) {
            const float ov = __shfl_xor(v,  off, 16);
            const int   om = __shfl_xor(mi, off, 16);
            if (ov > v || (ov == v && om < mi)) { v = ov; mi = om; }
        }
        if (lane == 0) s_e = c * NC_ + mi;
    }
    __syncthreads();
    const int e = s_e;

    // ---- r[b][j] = relu(x·W1r[e][j] + b1r), 100 rows, 2/wave/iter ----
    {
        const float4* xr = (const float4*)s_x;     // 512 float4
        for (int j0 = wave * 2; j0 < N3_; j0 += 32) {
            const float4* wr0 = (const float4*)(W1r + ((size_t)e * N3_ + j0) * N0_);
            const float4* wr1 = wr0 + (N0_ / 4);
            float a0 = 0.f, a1 = 0.f;
#pragma unroll
            for (int f = 0; f < 8; ++f) {
                const int idx = f * 64 + lane;
                const float4 xv = xr[idx];
                const float4 w0 = wr0[idx], w1 = wr1[idx];
                a0 += w0.x * xv.x + w0.y * xv.y + w0.z * xv.z + w0.w * xv.w;
                a1 += w1.x * xv.x + w1.y * xv.y + w1.z * xv.z + w1.w * xv.w;
            }
            const float s0 = wred(a0), s1 = wred(a1);
            if (lane == 0) {
                s_r[j0]     = fmaxf(s0 + b1r[e * N3_ + j0],     0.f);
                s_r[j0 + 1] = fmaxf(s1 + b1r[e * N3_ + j0 + 1], 0.f);
            }
        }
    }
    __syncthreads();

    // ---- y2[b][d] = r·W2r[e][d] + b2r, wave d handles d ----
    if (wave < 3) {
        const float* w2 = W2r + ((size_t)e * 3 + wave) * N3_;
        float a = s_r[lane] * w2[lane];
        if (lane < N3_ - 64) a += s_r[64 + lane] * w2[64 + lane];
        const float s = wred(a);
        if (lane == 0) out_y2[b * 3 + wave] = s + b2r[e * 3 + wave];
    }
}

extern "C" void kernel_launch(void* const* d_in, const int* in_sizes, int n_in,
                              void* d_out, int out_size, void* d_ws, size_t ws_size,
                              hipStream_t stream) {
    const float* x   = (const float*)d_in[0];
    const int*   cls = (const int*)  d_in[1];
    const float* W1b = (const float*)d_in[2];
    const float* b1b = (const float*)d_in[3];
    const float* W2b = (const float*)d_in[4];
    const float* b2b = (const float*)d_in[5];
    const float* W3b = (const float*)d_in[6];
    const float* b3b = (const float*)d_in[7];
    const float* W1r = (const float*)d_in[8];
    const float* b1r = (const float*)d_in[9];
    const float* W2r = (const float*)d_in[10];
    const float* b2r = (const float*)d_in[11];

    float* out_y1 = (float*)d_out;                 // [0, 1024)
    float* out_y2 = (float*)d_out + B_ * NC_;      // [1024, 1216)
    float* h1     = (float*)d_ws;                  // 256000 B

    hipLaunchKernelGGL(k_l1b, dim3(1500), dim3(256), 0, stream,
                       x, cls, W1b, b1b, h1);
    hipLaunchKernelGGL(k_perb, dim3(64), dim3(1024), 0, stream,
                       x, cls, h1, W2b, b2b, W3b, b3b, W1r, b1r, W2r, b2r,
                       out_y1, out_y2);
}